// Round 5
// baseline (110.016 us; speedup 1.0000x reference)
//
#include <hip/hip_runtime.h>
#include <stdint.h>

#define NTOK 256
#define NOUT 128
#define DIM 64
#define NB 128
#define CAP 1024
#define LCAP 512
#define NTILES 2080
#define TILES_PER_SUB 520
#define NMERGE 128
#define KAPPA 0.24f
#define SCREEN 0.2395f

__device__ __forceinline__ unsigned mono_f32(float s) {
  unsigned u = __float_as_uint(s);
  return (u & 0x80000000u) ? ~u : (u | 0x80000000u);
}

__device__ __forceinline__ unsigned long long shflx64(unsigned long long x, int m) {
  unsigned lo = (unsigned)x, hi = (unsigned)(x >> 32);
  lo = __shfl_xor(lo, m);
  hi = __shfl_xor(hi, m);
  return ((unsigned long long)hi << 32) | lo;
}

__device__ __forceinline__ void tile_ij(int T, int& tio, int& tjo) {
  float tf = (129.0f - sqrtf(129.0f * 129.0f - 8.0f * (float)T)) * 0.5f;
  int t = (int)tf;
  if (t < 0) t = 0;
  if (t > 63) t = 63;
  while (t < 63 && (t + 1) * (129 - (t + 1)) / 2 <= T) ++t;
  while (t > 0 && t * (129 - t) / 2 > T) --t;
  tio = t;
  tjo = t + (T - t * (129 - t) / 2);
}

// norm with EXACT same f64 accumulation grouping as gm_gram's normalize
__device__ __forceinline__ double knorm(const float* kp) {
  double s0 = 0.0, s1 = 0.0;
  for (int q = 0; q < 8; ++q) {
    const float* p = kp + q * 4;
    s0 += (double)p[0] * p[0] + (double)p[1] * p[1] +
          (double)p[2] * p[2] + (double)p[3] * p[3];
  }
  for (int q = 0; q < 8; ++q) {
    const float* p = kp + 32 + q * 4;
    s1 += (double)p[0] * p[0] + (double)p[1] * p[1] +
          (double)p[2] * p[2] + (double)p[3] * p[3];
  }
  return sqrt(s0 + s1);
}

#define CEX(a, b, up)                         \
  do {                                        \
    unsigned long long _a = (a), _b = (b);    \
    bool _sw = (up) ? (_a < _b) : (_a > _b);  \
    if (_sw) { (a) = _b; (b) = _a; }          \
  } while (0)

#define KEEP(v, o, km) ((km) ? ((v) > (o) ? (v) : (o)) : ((v) < (o) ? (v) : (o)))

// ============ kernel A: f32 gram screen + exact f64 rescreen + LDS collect ============
// grid 512 (4 WGs/batch), block 512. LDS: knT 64KB + lkeys 4KB + lmisc.
#define SMEM_A 69664
__global__ __launch_bounds__(512) void gm_gram(const float* __restrict__ K,
                                               unsigned* __restrict__ gcnt,
                                               unsigned* __restrict__ gflag,
                                               unsigned long long* __restrict__ gkeys) {
  extern __shared__ char smem[];
  float* knT = (float*)smem;
  unsigned long long* lkeys = (unsigned long long*)(smem + 65536);
  int* lmisc = (int*)(smem + 69632);

  const int tid = threadIdx.x;
  const int b = blockIdx.x >> 2, sub = blockIdx.x & 3;

  if (tid == 0) lmisc[0] = 0;

  // normalize -> knT[d][t] (bit-identical to prior rounds)
  {
    const int t = tid >> 1, h = tid & 1;
    const float* kp = K + ((size_t)b * NTOK + t) * DIM + h * 32;
    double ss = 0.0;
    float vals[32];
#pragma unroll
    for (int q = 0; q < 8; ++q) {
      float4 v4 = *reinterpret_cast<const float4*>(kp + q * 4);
      vals[q * 4 + 0] = v4.x; vals[q * 4 + 1] = v4.y;
      vals[q * 4 + 2] = v4.z; vals[q * 4 + 3] = v4.w;
      ss += (double)v4.x * v4.x + (double)v4.y * v4.y +
            (double)v4.z * v4.z + (double)v4.w * v4.w;
    }
    double other = __shfl_xor(ss, 1);
    double nrm = sqrt(ss + other);
#pragma unroll
    for (int q = 0; q < 32; ++q)
      knT[(h * 32 + q) * NTOK + t] = (float)((double)vals[q] / nrm);
  }
  __syncthreads();

  // f32 gram screen; exact f64 recompute for screened cells only.
  // |f32dot - f64dot| <= ~64*eps*|a||b| ~ 4e-6 << (KAPPA - SCREEN) = 5e-4,
  // so the collected key set is IDENTICAL to the full-f64 version.
  const int base = sub * TILES_PER_SUB;
  for (int t = tid; t < TILES_PER_SUB; t += 512) {
    const int T = base + t;
    int ti, tj;
    tile_ij(T, ti, tj);
    const int i0 = ti * 4, j0 = tj * 4;

    float acc[4][4] = {};
#pragma unroll 4
    for (int d = 0; d < 64; ++d) {
      const float4 av = *reinterpret_cast<const float4*>(knT + d * NTOK + i0);
      const float4 bv = *reinterpret_cast<const float4*>(knT + d * NTOK + j0);
      const float aa[4] = {av.x, av.y, av.z, av.w};
      const float bb[4] = {bv.x, bv.y, bv.z, bv.w};
#pragma unroll
      for (int r = 0; r < 4; ++r)
#pragma unroll
        for (int c = 0; c < 4; ++c)
          acc[r][c] = fmaf(aa[r], bb[c], acc[r][c]);
    }
#pragma unroll
    for (int r = 0; r < 4; ++r)
#pragma unroll
      for (int c = 0; c < 4; ++c) {
        const int i = i0 + r, j = j0 + c;
        if (i < j && acc[r][c] >= SCREEN) {
          double s = 0.0;
          for (int d = 0; d < 64; ++d)
            s = fma((double)knT[d * NTOK + i], (double)knT[d * NTOK + j], s);
          const float sf = (float)s;
          if (sf >= KAPPA) {
            const unsigned u = mono_f32(sf);
            const unsigned long long key =
                ((unsigned long long)u << 16) |
                (unsigned)(65535 - ((i << 8) | j));
            const int idx = atomicAdd(&lmisc[0], 1);
            if (idx < LCAP) lkeys[idx] = key;
          }
        }
      }
  }
  __syncthreads();

  // one global reservation per block, then coalesced flush
  if (tid == 0) {
    const int lc = lmisc[0];
    const int n = lc > LCAP ? LCAP : lc;
    const unsigned rsv = atomicAdd(&gcnt[b], (unsigned)lc);
    if (lc > LCAP) gflag[b] = 1u;
    lmisc[1] = (int)rsv;
    lmisc[2] = n;
  }
  __syncthreads();
  const int rsv = lmisc[1], n = lmisc[2];
  for (int e = tid; e < n; e += 512) {
    const int pos = rsv + e;
    if (pos < CAP) gkeys[(size_t)b * CAP + pos] = lkeys[e];
  }
}

// ============ kernel B: sort (LDS) + parallel-round walk + epilogue ============
// grid 128, block 256.
__global__ __launch_bounds__(256) void gm_sortwalk(const float* __restrict__ K,
                                                   const float* __restrict__ V,
                                                   float* __restrict__ OUT,
                                                   const unsigned* __restrict__ gcnt,
                                                   const unsigned* __restrict__ gflag,
                                                   const unsigned long long* __restrict__ gkeys) {
  __shared__ unsigned long long keys[CAP];   // 8KB
  __shared__ float accO[NOUT * DIM];         // 32KB
  __shared__ int gid[NTOK];
  __shared__ unsigned claimA[NTOK];
  __shared__ int gmap[NTOK];
  __shared__ int cnt256[NTOK];
  __shared__ int scn[NTOK];
  __shared__ int rep[NOUT];
  __shared__ int misc[4];
  __shared__ unsigned long long red[4];
  __shared__ unsigned long long bkey[1];

  const int tid = threadIdx.x;
  const int lane = tid & 63;
  const int wid = tid >> 6;
  const int b = blockIdx.x;

  const unsigned cntRaw = gcnt[b];
  const int cnt = cntRaw > CAP ? CAP : (int)cntRaw;
  const bool fullFB = (cntRaw > CAP) || (gflag[b] != 0u);

  if (tid == 0) misc[3] = fullFB ? 0 : NMERGE;
  gid[tid] = tid;
  claimA[tid] = 0xFFFFFFFFu;
  gmap[tid] = -1;
  cnt256[tid] = 0;
  for (int e = tid; e < NOUT * DIM; e += 256) accO[e] = 0.0f;

  // ---- load own 4 keys from global, bitonic sort (descending) in regs/LDS ----
  const int e0 = 4 * tid;
  {
    const unsigned long long* gk = gkeys + (size_t)b * CAP;
    unsigned long long v0 = (e0 + 0 < cnt) ? gk[e0 + 0] : 0ULL;
    unsigned long long v1 = (e0 + 1 < cnt) ? gk[e0 + 1] : 0ULL;
    unsigned long long v2 = (e0 + 2 < cnt) ? gk[e0 + 2] : 0ULL;
    unsigned long long v3 = (e0 + 3 < cnt) ? gk[e0 + 3] : 0ULL;

    for (int kk = 2; kk <= CAP; kk <<= 1) {
      for (int jj = kk >> 1; jj > 0; jj >>= 1) {
        if (jj >= 256) {
          __syncthreads();
          keys[e0] = v0; keys[e0 + 1] = v1; keys[e0 + 2] = v2; keys[e0 + 3] = v3;
          __syncthreads();
          const int p0 = e0 ^ jj;
          unsigned long long o0 = keys[p0], o1 = keys[p0 + 1],
                             o2 = keys[p0 + 2], o3 = keys[p0 + 3];
          const bool km = ((e0 & kk) == 0) == ((e0 & jj) == 0);
          v0 = KEEP(v0, o0, km); v1 = KEEP(v1, o1, km);
          v2 = KEEP(v2, o2, km); v3 = KEEP(v3, o3, km);
        } else if (jj >= 4) {
          const int m = jj >> 2;
          unsigned long long o0 = shflx64(v0, m), o1 = shflx64(v1, m),
                             o2 = shflx64(v2, m), o3 = shflx64(v3, m);
          const bool km = ((e0 & kk) == 0) == ((e0 & jj) == 0);
          v0 = KEEP(v0, o0, km); v1 = KEEP(v1, o1, km);
          v2 = KEEP(v2, o2, km); v3 = KEEP(v3, o3, km);
        } else if (jj == 2) {
          const bool up = ((e0 & kk) == 0);
          CEX(v0, v2, up); CEX(v1, v3, up);
        } else {
          bool up0, up1;
          if (kk == 2) { up0 = true; up1 = false; }
          else { up0 = up1 = ((e0 & kk) == 0); }
          CEX(v0, v1, up0); CEX(v2, v3, up1);
        }
      }
    }
    __syncthreads();
    keys[e0] = v0; keys[e0 + 1] = v1; keys[e0 + 2] = v2; keys[e0 + 3] = v3;
  }
  __syncthreads();

  // ---- wave-0 walk over sorted keys: parallel disjoint-merge rounds ----
  if (!fullFB && wid == 0) {
    int done = 0;
    for (int cursor = 0; cursor < cnt && done < NMERGE; cursor += 64) {
      const int idx = cursor + lane;
      const unsigned long long key = (idx < cnt) ? keys[idx] : 0ULL;
      const int pi = 255 - (int)((key >> 8) & 255);
      const int pj = 255 - (int)(key & 255);
      int gpi = gid[pi];
      int gpj = gid[pj];
      if (key == 0ULL) { gpi = 0; gpj = 0; }  // padding -> invalid
      // own tokens' groups in regs for this window
      int rg0 = gid[lane], rg1 = gid[64 + lane],
          rg2 = gid[128 + lane], rg3 = gid[192 + lane];

      unsigned long long valid = __ballot(gpi != gpj);
      if (done + (int)__popcll(valid) < NMERGE) {
        // -------- parallel rounds: commit all prefix-disjoint merges --------
        while (valid) {
          const bool v = (gpi != gpj);
          if (v) {
            atomicMin(&claimA[gpi], (unsigned)lane);
            atomicMin(&claimA[gpj], (unsigned)lane);
          }
          __threadfence_block();
          // winner: earliest valid claimer of BOTH its groups == exactly the
          // merges the sequential scan would perform before any conflicting edge
          const bool win = v && (claimA[gpi] == (unsigned)lane) &&
                           (claimA[gpj] == (unsigned)lane);
          if (win) gmap[gpi] = gpj;  // merge group gpi INTO gpj
          __threadfence_block();
          // relabel own tokens + own edge via one-step map (winners disjoint)
          const int ogpi = gpi, ogpj = gpj;
          {
            const int m0 = gmap[rg0], m1 = gmap[rg1],
                      m2 = gmap[rg2], m3 = gmap[rg3];
            const int mi = gmap[ogpi], mj = gmap[ogpj];
            if (m0 >= 0) rg0 = m0;
            if (m1 >= 0) rg1 = m1;
            if (m2 >= 0) rg2 = m2;
            if (m3 >= 0) rg3 = m3;
            if (mi >= 0) gpi = mi;
            if (mj >= 0) gpj = mj;
          }
          // cleanup for next round (same-wave DS ops are in-order)
          if (v) { claimA[ogpi] = 0xFFFFFFFFu; claimA[ogpj] = 0xFFFFFFFFu; }
          if (win) gmap[ogpi] = -1;
          __threadfence_block();
          done += (int)__popcll(__ballot(win));
          valid = __ballot(gpi != gpj);
        }
      } else {
        // -------- serial mode near budget: exact cutoff at NMERGE --------
        for (;;) {
          const unsigned long long mask = __ballot(gpi != gpj);
          if (!mask) break;
          const int f = __ffsll((long long)mask) - 1;
          const int gij = __shfl((gpi << 8) | gpj, f);
          const int gi = gij >> 8, gj = gij & 255;
          if (gpi == gi) gpi = gj;
          if (gpj == gi) gpj = gj;
          if (rg0 == gi) rg0 = gj;
          if (rg1 == gi) rg1 = gj;
          if (rg2 == gi) rg2 = gj;
          if (rg3 == gi) rg3 = gj;
          if (++done == NMERGE) break;
        }
      }
      // write back this window's relabels for the next window's gathers
      gid[lane] = rg0; gid[64 + lane] = rg1;
      gid[128 + lane] = rg2; gid[192 + lane] = rg3;
      __threadfence_block();
    }
    if (lane == 0) misc[3] = done;
  }
  __syncthreads();

  // ---- exact fallback (never taken in practice): argmax per remaining merge ----
  {
    const int start = misc[3];
    for (int mg = start; mg < NMERGE; ++mg) {
      unsigned long long best = 0ULL;
      const int p = tid >> 1, q = tid & 1;
      const int jA = 128 + p, jB = 127 - p;
      const int lenA = jA;
      const int s0 = q * 128, s1 = (q == 1) ? 255 : 128;
      for (int e = s0; e < s1; ++e) {
        const int i = (e < lenA) ? e : (e - lenA);
        const int j = (e < lenA) ? jA : jB;
        if (gid[i] != gid[j]) {
          const float* ki = K + ((size_t)b * NTOK + i) * DIM;
          const float* kj = K + ((size_t)b * NTOK + j) * DIM;
          const double ni = knorm(ki), nj = knorm(kj);
          double s = 0.0;
          for (int d = 0; d < 64; ++d) {
            const float ai = (float)((double)ki[d] / ni);
            const float aj = (float)((double)kj[d] / nj);
            s = fma((double)ai, (double)aj, s);
          }
          const unsigned u = mono_f32((float)s);
          const unsigned long long key =
              ((unsigned long long)u << 16) |
              (unsigned)(65535 - ((i << 8) | j));
          if (key > best) best = key;
        }
      }
#pragma unroll
      for (int off = 32; off; off >>= 1) {
        unsigned long long o = __shfl_down(best, off);
        if (o > best) best = o;
      }
      if (lane == 0) red[wid] = best;
      __syncthreads();
      if (tid == 0) {
        unsigned long long mx = red[0];
        for (int w = 1; w < 4; ++w)
          if (red[w] > mx) mx = red[w];
        bkey[0] = mx;
      }
      __syncthreads();
      const unsigned long long bk = bkey[0];
      const int pi = 255 - (int)((bk >> 8) & 255);
      const int pj = 255 - (int)(bk & 255);
      const int gi = gid[pi], gj = gid[pj];
      __syncthreads();
      if (gid[tid] == gi) gid[tid] = gj;
      __syncthreads();
    }
  }
  __syncthreads();

  // ---- sizes + single-wave prefix scan + slots ----
  atomicAdd(&cnt256[gid[tid]], 1);
  __syncthreads();
  if (wid == 0) {
    const int t4 = lane * 4;
    const int c0 = cnt256[t4 + 0] != 0, c1 = cnt256[t4 + 1] != 0,
              c2 = cnt256[t4 + 2] != 0, c3 = cnt256[t4 + 3] != 0;
    const int tot = c0 + c1 + c2 + c3;
    int run = tot;
#pragma unroll
    for (int off = 1; off < 64; off <<= 1) {
      int o = __shfl_up(run, off);
      if (lane >= off) run += o;
    }
    const int bs = run - tot;
    scn[t4 + 0] = bs + c0;
    scn[t4 + 1] = bs + c0 + c1;
    scn[t4 + 2] = bs + c0 + c1 + c2;
    scn[t4 + 3] = bs + tot;
  }
  __syncthreads();
  if (cnt256[tid]) rep[scn[tid] - 1] = tid;
  __syncthreads();

  // ---- accumulate V into slots (token tid) ----
  {
    const int slot = scn[gid[tid]] - 1;
    const float* vp = V + ((size_t)b * NTOK + tid) * DIM;
    float* dst = accO + slot * DIM;
#pragma unroll
    for (int q = 0; q < 16; ++q) {
      float4 v4 = *reinterpret_cast<const float4*>(vp + q * 4);
      atomicAdd(&dst[q * 4 + 0], v4.x);
      atomicAdd(&dst[q * 4 + 1], v4.y);
      atomicAdd(&dst[q * 4 + 2], v4.z);
      atomicAdd(&dst[q * 4 + 3], v4.w);
    }
  }
  __syncthreads();

  // ---- write outputs ----
  float* outMain = OUT + (size_t)b * (NOUT * DIM);
  for (int e = tid; e < NOUT * DIM; e += 256) {
    const int o = e >> 6;
    const float sz = (float)cnt256[rep[o]];
    outMain[e] = accO[e] / sz;
  }
  float* outSz = OUT + (size_t)NB * NOUT * DIM + (size_t)b * NOUT;
  if (tid < NOUT) outSz[tid] = (float)cnt256[rep[tid]];
}

// ============ monolithic fallback (known-passing shape, only if ws too small) ============
#define MCAP 2048
#define SMEM_MONO 118400
__global__ __launch_bounds__(512) void gm_mono(const float* __restrict__ K,
                                               const float* __restrict__ V,
                                               float* __restrict__ OUT) {
  extern __shared__ char smem[];
  float* knT = (float*)smem;
  unsigned long long* keys = (unsigned long long*)(smem + 65536);
  float* accO = (float*)(smem + 81920);
  int* gid = (int*)(smem + 114688);
  int* cnt256 = (int*)(smem + 115712);
  int* scn = (int*)(smem + 116736);
  int* rep = (int*)(smem + 117760);
  unsigned long long* red = (unsigned long long*)(smem + 118272);
  unsigned long long* bkey = (unsigned long long*)(smem + 118336);
  int* misc = (int*)(smem + 118344);

  const int tid = threadIdx.x;
  const int lane = tid & 63;
  const int wid = tid >> 6;
  const int b = blockIdx.x;

  for (int e = tid; e < MCAP; e += 512) keys[e] = 0ULL;
  if (tid < 256) gid[tid] = tid;
  if (tid == 0) misc[0] = 0;

  {
    const int t = tid >> 1, h = tid & 1;
    const float* kp = K + ((size_t)b * NTOK + t) * DIM + h * 32;
    double ss = 0.0;
    float vals[32];
#pragma unroll
    for (int q = 0; q < 8; ++q) {
      float4 v4 = *reinterpret_cast<const float4*>(kp + q * 4);
      vals[q * 4 + 0] = v4.x; vals[q * 4 + 1] = v4.y;
      vals[q * 4 + 2] = v4.z; vals[q * 4 + 3] = v4.w;
      ss += (double)v4.x * v4.x + (double)v4.y * v4.y +
            (double)v4.z * v4.z + (double)v4.w * v4.w;
    }
    double other = __shfl_xor(ss, 1);
    double nrm = sqrt(ss + other);
#pragma unroll
    for (int q = 0; q < 32; ++q)
      knT[(h * 32 + q) * NTOK + t] = (float)((double)vals[q] / nrm);
  }
  __syncthreads();

  for (int T = tid; T < NTILES; T += 512) {
    int ti, tj;
    tile_ij(T, ti, tj);
    int i0 = ti * 4, j0 = tj * 4;
    double acc[4][4] = {};
#pragma unroll 4
    for (int d = 0; d < 64; ++d) {
      const float4 av = *reinterpret_cast<const float4*>(knT + d * NTOK + i0);
      const float4 bv = *reinterpret_cast<const float4*>(knT + d * NTOK + j0);
      double aa[4] = {(double)av.x, (double)av.y, (double)av.z, (double)av.w};
      double bb[4] = {(double)bv.x, (double)bv.y, (double)bv.z, (double)bv.w};
#pragma unroll
      for (int r = 0; r < 4; ++r)
#pragma unroll
        for (int c = 0; c < 4; ++c)
          acc[r][c] = fma(aa[r], bb[c], acc[r][c]);
    }
#pragma unroll
    for (int r = 0; r < 4; ++r)
#pragma unroll
      for (int c = 0; c < 4; ++c) {
        int i = i0 + r, j = j0 + c;
        if (i < j) {
          float s = (float)acc[r][c];
          if (s >= KAPPA) {
            unsigned u = mono_f32(s);
            unsigned long long key =
                ((unsigned long long)u << 16) |
                (unsigned)(65535 - ((i << 8) | j));
            int idx = atomicAdd(&misc[0], 1);
            if (idx < MCAP) keys[idx] = key;
          }
        }
      }
  }
  __syncthreads();
  if (tid == 0) {
    int c = misc[0];
    misc[1] = c > MCAP ? MCAP : c;
    misc[2] = c > MCAP ? 1 : 0;
    misc[3] = c > MCAP ? 0 : NMERGE;
  }
  __syncthreads();

  {
    const int e0 = 4 * tid;
    unsigned long long v0 = keys[e0], v1 = keys[e0 + 1],
                       v2 = keys[e0 + 2], v3 = keys[e0 + 3];
    for (int kk = 2; kk <= MCAP; kk <<= 1) {
      for (int jj = kk >> 1; jj > 0; jj >>= 1) {
        if (jj >= 256) {
          __syncthreads();
          keys[e0] = v0; keys[e0 + 1] = v1; keys[e0 + 2] = v2; keys[e0 + 3] = v3;
          __syncthreads();
          const int p0 = e0 ^ jj;
          unsigned long long o0 = keys[p0], o1 = keys[p0 + 1],
                             o2 = keys[p0 + 2], o3 = keys[p0 + 3];
          const bool km = ((e0 & kk) == 0) == ((e0 & jj) == 0);
          v0 = KEEP(v0, o0, km); v1 = KEEP(v1, o1, km);
          v2 = KEEP(v2, o2, km); v3 = KEEP(v3, o3, km);
        } else if (jj >= 4) {
          const int m = jj >> 2;
          unsigned long long o0 = shflx64(v0, m), o1 = shflx64(v1, m),
                             o2 = shflx64(v2, m), o3 = shflx64(v3, m);
          const bool km = ((e0 & kk) == 0) == ((e0 & jj) == 0);
          v0 = KEEP(v0, o0, km); v1 = KEEP(v1, o1, km);
          v2 = KEEP(v2, o2, km); v3 = KEEP(v3, o3, km);
        } else if (jj == 2) {
          const bool up = ((e0 & kk) == 0);
          CEX(v0, v2, up); CEX(v1, v3, up);
        } else {
          bool up0, up1;
          if (kk == 2) { up0 = true; up1 = false; }
          else { up0 = up1 = ((e0 & kk) == 0); }
          CEX(v0, v1, up0); CEX(v2, v3, up1);
        }
      }
    }
    __syncthreads();
    keys[e0] = v0; keys[e0 + 1] = v1; keys[e0 + 2] = v2; keys[e0 + 3] = v3;
  }
  __syncthreads();

  if (misc[2] == 0 && wid == 0) {
    const int cntC = misc[1];
    int rg0 = lane, rg1 = 64 + lane, rg2 = 128 + lane, rg3 = 192 + lane;
    int done = 0;
    for (int cursor = 0; cursor < cntC && done < NMERGE; cursor += 64) {
      const int idx = cursor + lane;
      const unsigned long long key = (idx < cntC) ? keys[idx] : 0ULL;
      const int pi = 255 - (int)((key >> 8) & 255);
      const int pj = 255 - (int)(key & 255);
      const int sli = pi & 63, ssi = pi >> 6;
      const int slj = pj & 63, ssj = pj >> 6;
      const int a0 = __shfl(rg0, sli), a1 = __shfl(rg1, sli),
                a2 = __shfl(rg2, sli), a3 = __shfl(rg3, sli);
      const int b0 = __shfl(rg0, slj), b1 = __shfl(rg1, slj),
                b2 = __shfl(rg2, slj), b3 = __shfl(rg3, slj);
      int gpi = (ssi == 0) ? a0 : (ssi == 1) ? a1 : (ssi == 2) ? a2 : a3;
      int gpj = (ssj == 0) ? b0 : (ssj == 1) ? b1 : (ssj == 2) ? b2 : b3;
      if (key == 0ULL) { gpi = 0; gpj = 0; }
      for (;;) {
        const unsigned long long mask = __ballot(gpi != gpj);
        if (!mask) break;
        const int f = __ffsll((long long)mask) - 1;
        const int gi = __shfl(gpi, f), gj = __shfl(gpj, f);
        if (lane == f) gpi = gpj;
        if (gpi == gi) gpi = gj;
        if (gpj == gi) gpj = gj;
        if (rg0 == gi) rg0 = gj;
        if (rg1 == gi) rg1 = gj;
        if (rg2 == gi) rg2 = gj;
        if (rg3 == gi) rg3 = gj;
        if (++done == NMERGE) break;
      }
    }
    gid[lane] = rg0; gid[64 + lane] = rg1;
    gid[128 + lane] = rg2; gid[192 + lane] = rg3;
    if (lane == 0) misc[3] = done;
  }
  __syncthreads();

  {
    const int start = misc[3];
    for (int mg = start; mg < NMERGE; ++mg) {
      unsigned long long best = 0ULL;
      const int p = tid >> 2, q = tid & 3;
      const int jA = 128 + p, jB = 127 - p;
      const int lenA = jA;
      int s0 = q * 64, s1 = (q == 3) ? 255 : (q * 64 + 64);
      for (int e = s0; e < s1; ++e) {
        int i = (e < lenA) ? e : (e - lenA);
        int j = (e < lenA) ? jA : jB;
        if (gid[i] != gid[j]) {
          double s = 0.0;
          for (int d = 0; d < 64; ++d)
            s = fma((double)knT[d * NTOK + i], (double)knT[d * NTOK + j], s);
          unsigned u = mono_f32((float)s);
          unsigned long long key =
              ((unsigned long long)u << 16) |
              (unsigned)(65535 - ((i << 8) | j));
          if (key > best) best = key;
        }
      }
#pragma unroll
      for (int off = 32; off; off >>= 1) {
        unsigned long long o = __shfl_down(best, off);
        if (o > best) best = o;
      }
      if (lane == 0) red[wid] = best;
      __syncthreads();
      if (tid == 0) {
        unsigned long long mx = 0ULL;
        for (int w = 0; w < 8; ++w)
          if (red[w] > mx) mx = red[w];
        bkey[0] = mx;
      }
      __syncthreads();
      unsigned long long bk = bkey[0];
      int pi = 255 - (int)((bk >> 8) & 255);
      int pj = 255 - (int)(bk & 255);
      int gi = gid[pi], gj = gid[pj];
      __syncthreads();
      if (tid < 256 && gid[tid] == gi) gid[tid] = gj;
      __syncthreads();
    }
  }
  __syncthreads();

  if (tid < 256) cnt256[tid] = 0;
  __syncthreads();
  if (tid < 256) atomicAdd(&cnt256[gid[tid]], 1);
  __syncthreads();
  if (wid == 0) {
    const int t4 = lane * 4;
    const int c0 = cnt256[t4 + 0] != 0, c1 = cnt256[t4 + 1] != 0,
              c2 = cnt256[t4 + 2] != 0, c3 = cnt256[t4 + 3] != 0;
    const int tot = c0 + c1 + c2 + c3;
    int run = tot;
#pragma unroll
    for (int off = 1; off < 64; off <<= 1) {
      int o = __shfl_up(run, off);
      if (lane >= off) run += o;
    }
    const int bs = run - tot;
    scn[t4 + 0] = bs + c0;
    scn[t4 + 1] = bs + c0 + c1;
    scn[t4 + 2] = bs + c0 + c1 + c2;
    scn[t4 + 3] = bs + tot;
  }
  __syncthreads();
  if (tid < 256 && cnt256[tid]) rep[scn[tid] - 1] = tid;
  __syncthreads();
  for (int e = tid; e < NOUT * DIM; e += 512) accO[e] = 0.0f;
  __syncthreads();
  {
    const int t = tid >> 1, h = tid & 1;
    const int slot = scn[gid[t]] - 1;
    const float* vp = V + ((size_t)b * NTOK + t) * DIM + h * 32;
    float* dst = accO + slot * DIM + h * 32;
#pragma unroll
    for (int q = 0; q < 8; ++q) {
      float4 v4 = *reinterpret_cast<const float4*>(vp + q * 4);
      atomicAdd(&dst[q * 4 + 0], v4.x);
      atomicAdd(&dst[q * 4 + 1], v4.y);
      atomicAdd(&dst[q * 4 + 2], v4.z);
      atomicAdd(&dst[q * 4 + 3], v4.w);
    }
  }
  __syncthreads();

  float* outMain = OUT + (size_t)b * (NOUT * DIM);
  for (int e = tid; e < NOUT * DIM; e += 512) {
    int o = e >> 6;
    float sz = (float)cnt256[rep[o]];
    outMain[e] = accO[e] / sz;
  }
  float* outSz = OUT + (size_t)NB * NOUT * DIM + (size_t)b * NOUT;
  for (int o = tid; o < NOUT; o += 512) outSz[o] = (float)cnt256[rep[o]];
}

extern "C" void kernel_launch(void* const* d_in, const int* in_sizes, int n_in,
                              void* d_out, int out_size, void* d_ws, size_t ws_size,
                              hipStream_t stream) {
  const float* K = (const float*)d_in[0];
  const float* V = (const float*)d_in[1];
  float* OUT = (float*)d_out;
  (void)in_sizes; (void)n_in; (void)out_size;

  // ws layout: gcnt[128] u32 @0 (512B), gflag[128] u32 @512 (512B), gkeys @1024
  const size_t need = 1024 + (size_t)NB * CAP * sizeof(unsigned long long);
  if (ws_size >= need) {
    unsigned* gcnt = (unsigned*)d_ws;
    unsigned* gflag = (unsigned*)((char*)d_ws + 512);
    unsigned long long* gkeys = (unsigned long long*)((char*)d_ws + 1024);
    hipMemsetAsync(d_ws, 0, 1024, stream);
    hipFuncSetAttribute(reinterpret_cast<const void*>(gm_gram),
                        hipFuncAttributeMaxDynamicSharedMemorySize, SMEM_A);
    gm_gram<<<dim3(NB * 4), dim3(512), SMEM_A, stream>>>(K, gcnt, gflag, gkeys);
    gm_sortwalk<<<dim3(NB), dim3(256), 0, stream>>>(K, V, OUT, gcnt, gflag, gkeys);
  } else {
    hipFuncSetAttribute(reinterpret_cast<const void*>(gm_mono),
                        hipFuncAttributeMaxDynamicSharedMemorySize, SMEM_MONO);
    gm_mono<<<dim3(NB), dim3(512), SMEM_MONO, stream>>>(K, V, OUT);
  }
}

// Round 6
// 84.947 us; speedup vs baseline: 1.2951x; 1.2951x over previous
//
#include <hip/hip_runtime.h>
#include <stdint.h>

#define NTOK 256
#define NOUT 128
#define DIM 64
#define NB 128
#define CAP 1024
#define PCAP 1024
#define NMERGE 128
#define KAPPA 0.24f
#define SCREEN 0.2395f
#define NTILES84 1056
#define TILES_PER_SUB84 528

__device__ __forceinline__ unsigned mono_f32(float s) {
  unsigned u = __float_as_uint(s);
  return (u & 0x80000000u) ? ~u : (u | 0x80000000u);
}

__device__ __forceinline__ unsigned long long shflx64(unsigned long long x, int m) {
  unsigned lo = (unsigned)x, hi = (unsigned)(x >> 32);
  lo = __shfl_xor(lo, m);
  hi = __shfl_xor(hi, m);
  return ((unsigned long long)hi << 32) | lo;
}

// invert T -> (ti, tj) on the 8x4 tile grid: ti in [0,32), tj in [2*ti, 64)
// cum(ti) = 65*ti - ti*ti
__device__ __forceinline__ void tile84(int T, int& tio, int& tjo) {
  float tf = (65.0f - sqrtf(4225.0f - 4.0f * (float)T)) * 0.5f;
  int t = (int)tf;
  if (t < 0) t = 0;
  if (t > 31) t = 31;
  while (t < 31 && 65 * (t + 1) - (t + 1) * (t + 1) <= T) ++t;
  while (t > 0 && 65 * t - t * t > T) --t;
  tio = t;
  tjo = 2 * t + (T - (65 * t - t * t));
}

// 4x4 tile inversion (used by mono fallback only)
__device__ __forceinline__ void tile_ij(int T, int& tio, int& tjo) {
  float tf = (129.0f - sqrtf(129.0f * 129.0f - 8.0f * (float)T)) * 0.5f;
  int t = (int)tf;
  if (t < 0) t = 0;
  if (t > 63) t = 63;
  while (t < 63 && (t + 1) * (129 - (t + 1)) / 2 <= T) ++t;
  while (t > 0 && t * (129 - t) / 2 > T) --t;
  tio = t;
  tjo = t + (T - t * (129 - t) / 2);
}

// norm with EXACT same f64 accumulation grouping as gm_gram's normalize
__device__ __forceinline__ double knorm(const float* kp) {
  double s0 = 0.0, s1 = 0.0;
  for (int q = 0; q < 8; ++q) {
    const float* p = kp + q * 4;
    s0 += (double)p[0] * p[0] + (double)p[1] * p[1] +
          (double)p[2] * p[2] + (double)p[3] * p[3];
  }
  for (int q = 0; q < 8; ++q) {
    const float* p = kp + 32 + q * 4;
    s1 += (double)p[0] * p[0] + (double)p[1] * p[1] +
          (double)p[2] * p[2] + (double)p[3] * p[3];
  }
  return sqrt(s0 + s1);
}

#define CEX(a, b, up)                         \
  do {                                        \
    unsigned long long _a = (a), _b = (b);    \
    bool _sw = (up) ? (_a < _b) : (_a > _b);  \
    if (_sw) { (a) = _b; (b) = _a; }          \
  } while (0)

#define KEEP(v, o, km) ((km) ? ((v) > (o) ? (v) : (o)) : ((v) < (o) ? (v) : (o)))

// ============ kernel A: 8x4-tile f32 gram screen -> pair list -> compact f64 keys ============
// grid 256 (2 WGs/batch), block 512.
// LDS: knT 64KB @0, lpairs 4KB @65536, lkeys 8KB @69632, lmisc @77824
#define SMEM_A 77856
__global__ __launch_bounds__(512) void gm_gram(const float* __restrict__ K,
                                               unsigned* __restrict__ gcnt,
                                               unsigned* __restrict__ gflag,
                                               unsigned long long* __restrict__ gkeys) {
  extern __shared__ char smem[];
  float* knT = (float*)smem;
  unsigned* lpairs = (unsigned*)(smem + 65536);
  unsigned long long* lkeys = (unsigned long long*)(smem + 69632);
  int* lmisc = (int*)(smem + 77824);

  const int tid = threadIdx.x;
  const int b = blockIdx.x >> 1, sub = blockIdx.x & 1;

  if (tid == 0) { lmisc[0] = 0; lmisc[1] = 0; }

  // normalize -> knT[d][t] (bit-identical to prior rounds)
  {
    const int t = tid >> 1, h = tid & 1;
    const float* kp = K + ((size_t)b * NTOK + t) * DIM + h * 32;
    double ss = 0.0;
    float vals[32];
#pragma unroll
    for (int q = 0; q < 8; ++q) {
      float4 v4 = *reinterpret_cast<const float4*>(kp + q * 4);
      vals[q * 4 + 0] = v4.x; vals[q * 4 + 1] = v4.y;
      vals[q * 4 + 2] = v4.z; vals[q * 4 + 3] = v4.w;
      ss += (double)v4.x * v4.x + (double)v4.y * v4.y +
            (double)v4.z * v4.z + (double)v4.w * v4.w;
    }
    double other = __shfl_xor(ss, 1);
    double nrm = sqrt(ss + other);
#pragma unroll
    for (int q = 0; q < 32; ++q)
      knT[(h * 32 + q) * NTOK + t] = (float)((double)vals[q] / nrm);
  }
  __syncthreads();

  // ---- f32 screen over 8x4 register tiles; push (i,j) pairs to LDS ----
  // Per-cell acc chain is fmaf over ascending d: bit-identical to previous
  // rounds' screen, so the screened set is unchanged.
  const int base = sub * TILES_PER_SUB84;
  for (int t = tid; t < TILES_PER_SUB84; t += 512) {
    const int T = base + t;
    int ti, tj;
    tile84(T, ti, tj);
    const int i0 = ti * 8, j0 = tj * 4;

    float acc[8][4] = {};
#pragma unroll 4
    for (int d = 0; d < 64; ++d) {
      const float* row = knT + d * NTOK;
      const float4 a0 = *reinterpret_cast<const float4*>(row + i0);
      const float4 a1 = *reinterpret_cast<const float4*>(row + i0 + 4);
      const float4 bv = *reinterpret_cast<const float4*>(row + j0);
      const float aa[8] = {a0.x, a0.y, a0.z, a0.w, a1.x, a1.y, a1.z, a1.w};
      const float bb[4] = {bv.x, bv.y, bv.z, bv.w};
#pragma unroll
      for (int r = 0; r < 8; ++r)
#pragma unroll
        for (int c = 0; c < 4; ++c)
          acc[r][c] = fmaf(aa[r], bb[c], acc[r][c]);
    }
#pragma unroll
    for (int r = 0; r < 8; ++r)
#pragma unroll
      for (int c = 0; c < 4; ++c) {
        const int i = i0 + r, j = j0 + c;
        if (i < j && acc[r][c] >= SCREEN) {
          const int idx = atomicAdd(&lmisc[0], 1);
          if (idx < PCAP) lpairs[idx] = (unsigned)((i << 8) | j);
        }
      }
  }
  __syncthreads();

  // ---- compact exact-f64 recompute (no divergence, all threads busy) ----
  const int npRaw = lmisc[0];
  const int np = npRaw > PCAP ? PCAP : npRaw;
  for (int e = tid; e < np; e += 512) {
    const unsigned p = lpairs[e];
    const int i = (int)(p >> 8), j = (int)(p & 255u);
    double s = 0.0;
    for (int d = 0; d < 64; ++d)
      s = fma((double)knT[d * NTOK + i], (double)knT[d * NTOK + j], s);
    const float sf = (float)s;
    if (sf >= KAPPA) {
      const unsigned long long key =
          ((unsigned long long)mono_f32(sf) << 16) |
          (unsigned)(65535 - ((i << 8) | j));
      const int idx = atomicAdd(&lmisc[1], 1);
      lkeys[idx] = key;  // idx < np <= PCAP always
    }
  }
  __syncthreads();

  // ---- one global reservation per WG, coalesced flush ----
  if (tid == 0) {
    const int nk = lmisc[1];
    const unsigned rsv = atomicAdd(&gcnt[b], (unsigned)nk);
    if (npRaw > PCAP || rsv + (unsigned)nk > CAP) gflag[b] = 1u;
    lmisc[2] = (int)rsv;
    lmisc[3] = nk;
  }
  __syncthreads();
  const int rsv = lmisc[2], nk = lmisc[3];
  for (int e = tid; e < nk; e += 512) {
    const int pos = rsv + e;
    if (pos < CAP) gkeys[(size_t)b * CAP + pos] = lkeys[e];
  }
}

// ============ kernel B: sort (LDS) + parallel-round walk -> gid to ws ============
// grid 128, block 256.
__global__ __launch_bounds__(256) void gm_sortwalk(const float* __restrict__ K,
                                                   const unsigned* __restrict__ gcnt,
                                                   const unsigned* __restrict__ gflag,
                                                   const unsigned long long* __restrict__ gkeys,
                                                   int* __restrict__ gidg) {
  __shared__ unsigned long long keys[CAP];   // 8KB
  __shared__ int gid[NTOK];
  __shared__ unsigned claimA[NTOK];
  __shared__ int gmap[NTOK];
  __shared__ int misc[4];
  __shared__ unsigned long long red[4];
  __shared__ unsigned long long bkey[1];

  const int tid = threadIdx.x;
  const int lane = tid & 63;
  const int wid = tid >> 6;
  const int b = blockIdx.x;

  const unsigned cntRaw = gcnt[b];
  const int cnt = cntRaw > CAP ? CAP : (int)cntRaw;
  const bool fullFB = (cntRaw > CAP) || (gflag[b] != 0u);

  if (tid == 0) misc[3] = fullFB ? 0 : NMERGE;
  gid[tid] = tid;
  claimA[tid] = 0xFFFFFFFFu;
  gmap[tid] = -1;

  // ---- load own 4 keys, bitonic sort (descending) in regs/LDS ----
  const int e0 = 4 * tid;
  {
    const unsigned long long* gk = gkeys + (size_t)b * CAP;
    unsigned long long v0 = (e0 + 0 < cnt) ? gk[e0 + 0] : 0ULL;
    unsigned long long v1 = (e0 + 1 < cnt) ? gk[e0 + 1] : 0ULL;
    unsigned long long v2 = (e0 + 2 < cnt) ? gk[e0 + 2] : 0ULL;
    unsigned long long v3 = (e0 + 3 < cnt) ? gk[e0 + 3] : 0ULL;

    for (int kk = 2; kk <= CAP; kk <<= 1) {
      for (int jj = kk >> 1; jj > 0; jj >>= 1) {
        if (jj >= 256) {
          __syncthreads();
          keys[e0] = v0; keys[e0 + 1] = v1; keys[e0 + 2] = v2; keys[e0 + 3] = v3;
          __syncthreads();
          const int p0 = e0 ^ jj;
          unsigned long long o0 = keys[p0], o1 = keys[p0 + 1],
                             o2 = keys[p0 + 2], o3 = keys[p0 + 3];
          const bool km = ((e0 & kk) == 0) == ((e0 & jj) == 0);
          v0 = KEEP(v0, o0, km); v1 = KEEP(v1, o1, km);
          v2 = KEEP(v2, o2, km); v3 = KEEP(v3, o3, km);
        } else if (jj >= 4) {
          const int m = jj >> 2;
          unsigned long long o0 = shflx64(v0, m), o1 = shflx64(v1, m),
                             o2 = shflx64(v2, m), o3 = shflx64(v3, m);
          const bool km = ((e0 & kk) == 0) == ((e0 & jj) == 0);
          v0 = KEEP(v0, o0, km); v1 = KEEP(v1, o1, km);
          v2 = KEEP(v2, o2, km); v3 = KEEP(v3, o3, km);
        } else if (jj == 2) {
          const bool up = ((e0 & kk) == 0);
          CEX(v0, v2, up); CEX(v1, v3, up);
        } else {
          bool up0, up1;
          if (kk == 2) { up0 = true; up1 = false; }
          else { up0 = up1 = ((e0 & kk) == 0); }
          CEX(v0, v1, up0); CEX(v2, v3, up1);
        }
      }
    }
    __syncthreads();
    keys[e0] = v0; keys[e0 + 1] = v1; keys[e0 + 2] = v2; keys[e0 + 3] = v3;
  }
  __syncthreads();

  // ---- wave-0 walk over sorted keys: parallel disjoint-merge rounds ----
  if (!fullFB && wid == 0) {
    int done = 0;
    for (int cursor = 0; cursor < cnt && done < NMERGE; cursor += 64) {
      const int idx = cursor + lane;
      const unsigned long long key = (idx < cnt) ? keys[idx] : 0ULL;
      const int pi = 255 - (int)((key >> 8) & 255);
      const int pj = 255 - (int)(key & 255);
      int gpi = gid[pi];
      int gpj = gid[pj];
      if (key == 0ULL) { gpi = 0; gpj = 0; }  // padding -> invalid
      int rg0 = gid[lane], rg1 = gid[64 + lane],
          rg2 = gid[128 + lane], rg3 = gid[192 + lane];

      unsigned long long valid = __ballot(gpi != gpj);
      if (done + (int)__popcll(valid) < NMERGE) {
        // parallel rounds: commit all prefix-disjoint merges
        while (valid) {
          const bool v = (gpi != gpj);
          if (v) {
            atomicMin(&claimA[gpi], (unsigned)lane);
            atomicMin(&claimA[gpj], (unsigned)lane);
          }
          __threadfence_block();
          const bool win = v && (claimA[gpi] == (unsigned)lane) &&
                           (claimA[gpj] == (unsigned)lane);
          if (win) gmap[gpi] = gpj;
          __threadfence_block();
          const int ogpi = gpi, ogpj = gpj;
          {
            const int m0 = gmap[rg0], m1 = gmap[rg1],
                      m2 = gmap[rg2], m3 = gmap[rg3];
            const int mi = gmap[ogpi], mj = gmap[ogpj];
            if (m0 >= 0) rg0 = m0;
            if (m1 >= 0) rg1 = m1;
            if (m2 >= 0) rg2 = m2;
            if (m3 >= 0) rg3 = m3;
            if (mi >= 0) gpi = mi;
            if (mj >= 0) gpj = mj;
          }
          if (v) { claimA[ogpi] = 0xFFFFFFFFu; claimA[ogpj] = 0xFFFFFFFFu; }
          if (win) gmap[ogpi] = -1;
          __threadfence_block();
          done += (int)__popcll(__ballot(win));
          valid = __ballot(gpi != gpj);
        }
      } else {
        // serial mode near budget: exact cutoff at NMERGE
        for (;;) {
          const unsigned long long mask = __ballot(gpi != gpj);
          if (!mask) break;
          const int f = __ffsll((long long)mask) - 1;
          const int gij = __shfl((gpi << 8) | gpj, f);
          const int gi = gij >> 8, gj = gij & 255;
          if (gpi == gi) gpi = gj;
          if (gpj == gi) gpj = gj;
          if (rg0 == gi) rg0 = gj;
          if (rg1 == gi) rg1 = gj;
          if (rg2 == gi) rg2 = gj;
          if (rg3 == gi) rg3 = gj;
          if (++done == NMERGE) break;
        }
      }
      gid[lane] = rg0; gid[64 + lane] = rg1;
      gid[128 + lane] = rg2; gid[192 + lane] = rg3;
      __threadfence_block();
    }
    if (lane == 0) misc[3] = done;
  }
  __syncthreads();

  // ---- exact fallback (never taken in practice): argmax per remaining merge ----
  {
    const int start = misc[3];
    for (int mg = start; mg < NMERGE; ++mg) {
      unsigned long long best = 0ULL;
      const int p = tid >> 1, q = tid & 1;
      const int jA = 128 + p, jB = 127 - p;
      const int lenA = jA;
      const int s0 = q * 128, s1 = (q == 1) ? 255 : 128;
      for (int e = s0; e < s1; ++e) {
        const int i = (e < lenA) ? e : (e - lenA);
        const int j = (e < lenA) ? jA : jB;
        if (gid[i] != gid[j]) {
          const float* ki = K + ((size_t)b * NTOK + i) * DIM;
          const float* kj = K + ((size_t)b * NTOK + j) * DIM;
          const double ni = knorm(ki), nj = knorm(kj);
          double s = 0.0;
          for (int d = 0; d < 64; ++d) {
            const float ai = (float)((double)ki[d] / ni);
            const float aj = (float)((double)kj[d] / nj);
            s = fma((double)ai, (double)aj, s);
          }
          const unsigned long long key =
              ((unsigned long long)mono_f32((float)s) << 16) |
              (unsigned)(65535 - ((i << 8) | j));
          if (key > best) best = key;
        }
      }
#pragma unroll
      for (int off = 32; off; off >>= 1) {
        unsigned long long o = __shfl_down(best, off);
        if (o > best) best = o;
      }
      if (lane == 0) red[wid] = best;
      __syncthreads();
      if (tid == 0) {
        unsigned long long mx = red[0];
        for (int w = 1; w < 4; ++w)
          if (red[w] > mx) mx = red[w];
        bkey[0] = mx;
      }
      __syncthreads();
      const unsigned long long bk = bkey[0];
      const int pi = 255 - (int)((bk >> 8) & 255);
      const int pj = 255 - (int)(bk & 255);
      const int gi = gid[pi], gj = gid[pj];
      __syncthreads();
      if (gid[tid] == gi) gid[tid] = gj;
      __syncthreads();
    }
  }
  __syncthreads();

  gidg[b * NTOK + tid] = gid[tid];
}

// ============ kernel C: epilogue (sizes, slots, V means, outputs) ============
// grid 128, block 256.
__global__ __launch_bounds__(256) void gm_epi(const float* __restrict__ V,
                                              float* __restrict__ OUT,
                                              const int* __restrict__ gidg) {
  __shared__ float accO[NOUT * DIM];  // 32KB
  __shared__ int gid[NTOK];
  __shared__ int cnt256[NTOK];
  __shared__ int scn[NTOK];
  __shared__ int rep[NOUT];

  const int tid = threadIdx.x;
  const int lane = tid & 63;
  const int wid = tid >> 6;
  const int b = blockIdx.x;

  gid[tid] = gidg[b * NTOK + tid];
  cnt256[tid] = 0;
  for (int e = tid; e < NOUT * DIM; e += 256) accO[e] = 0.0f;
  __syncthreads();

  atomicAdd(&cnt256[gid[tid]], 1);
  __syncthreads();

  if (wid == 0) {
    const int t4 = lane * 4;
    const int c0 = cnt256[t4 + 0] != 0, c1 = cnt256[t4 + 1] != 0,
              c2 = cnt256[t4 + 2] != 0, c3 = cnt256[t4 + 3] != 0;
    const int tot = c0 + c1 + c2 + c3;
    int run = tot;
#pragma unroll
    for (int off = 1; off < 64; off <<= 1) {
      int o = __shfl_up(run, off);
      if (lane >= off) run += o;
    }
    const int bs = run - tot;
    scn[t4 + 0] = bs + c0;
    scn[t4 + 1] = bs + c0 + c1;
    scn[t4 + 2] = bs + c0 + c1 + c2;
    scn[t4 + 3] = bs + tot;
  }
  __syncthreads();
  if (cnt256[tid]) rep[scn[tid] - 1] = tid;
  __syncthreads();

  {
    const int slot = scn[gid[tid]] - 1;
    const float* vp = V + ((size_t)b * NTOK + tid) * DIM;
    float* dst = accO + slot * DIM;
#pragma unroll
    for (int q = 0; q < 16; ++q) {
      float4 v4 = *reinterpret_cast<const float4*>(vp + q * 4);
      atomicAdd(&dst[q * 4 + 0], v4.x);
      atomicAdd(&dst[q * 4 + 1], v4.y);
      atomicAdd(&dst[q * 4 + 2], v4.z);
      atomicAdd(&dst[q * 4 + 3], v4.w);
    }
  }
  __syncthreads();

  float* outMain = OUT + (size_t)b * (NOUT * DIM);
  for (int e = tid; e < NOUT * DIM; e += 256) {
    const int o = e >> 6;
    const float sz = (float)cnt256[rep[o]];
    outMain[e] = accO[e] / sz;
  }
  float* outSz = OUT + (size_t)NB * NOUT * DIM + (size_t)b * NOUT;
  if (tid < NOUT) outSz[tid] = (float)cnt256[rep[tid]];
}

// ============ monolithic fallback (known-passing shape, only if ws too small) ============
#define MCAP 2048
#define NTILES44 2080
#define SMEM_MONO 118400
__global__ __launch_bounds__(512) void gm_mono(const float* __restrict__ K,
                                               const float* __restrict__ V,
                                               float* __restrict__ OUT) {
  extern __shared__ char smem[];
  float* knT = (float*)smem;
  unsigned long long* keys = (unsigned long long*)(smem + 65536);
  float* accO = (float*)(smem + 81920);
  int* gid = (int*)(smem + 114688);
  int* cnt256 = (int*)(smem + 115712);
  int* scn = (int*)(smem + 116736);
  int* rep = (int*)(smem + 117760);
  unsigned long long* red = (unsigned long long*)(smem + 118272);
  unsigned long long* bkey = (unsigned long long*)(smem + 118336);
  int* misc = (int*)(smem + 118344);

  const int tid = threadIdx.x;
  const int lane = tid & 63;
  const int wid = tid >> 6;
  const int b = blockIdx.x;

  for (int e = tid; e < MCAP; e += 512) keys[e] = 0ULL;
  if (tid < 256) gid[tid] = tid;
  if (tid == 0) misc[0] = 0;

  {
    const int t = tid >> 1, h = tid & 1;
    const float* kp = K + ((size_t)b * NTOK + t) * DIM + h * 32;
    double ss = 0.0;
    float vals[32];
#pragma unroll
    for (int q = 0; q < 8; ++q) {
      float4 v4 = *reinterpret_cast<const float4*>(kp + q * 4);
      vals[q * 4 + 0] = v4.x; vals[q * 4 + 1] = v4.y;
      vals[q * 4 + 2] = v4.z; vals[q * 4 + 3] = v4.w;
      ss += (double)v4.x * v4.x + (double)v4.y * v4.y +
            (double)v4.z * v4.z + (double)v4.w * v4.w;
    }
    double other = __shfl_xor(ss, 1);
    double nrm = sqrt(ss + other);
#pragma unroll
    for (int q = 0; q < 32; ++q)
      knT[(h * 32 + q) * NTOK + t] = (float)((double)vals[q] / nrm);
  }
  __syncthreads();

  for (int T = tid; T < NTILES44; T += 512) {
    int ti, tj;
    tile_ij(T, ti, tj);
    int i0 = ti * 4, j0 = tj * 4;
    double acc[4][4] = {};
#pragma unroll 4
    for (int d = 0; d < 64; ++d) {
      const float4 av = *reinterpret_cast<const float4*>(knT + d * NTOK + i0);
      const float4 bv = *reinterpret_cast<const float4*>(knT + d * NTOK + j0);
      double aa[4] = {(double)av.x, (double)av.y, (double)av.z, (double)av.w};
      double bb[4] = {(double)bv.x, (double)bv.y, (double)bv.z, (double)bv.w};
#pragma unroll
      for (int r = 0; r < 4; ++r)
#pragma unroll
        for (int c = 0; c < 4; ++c)
          acc[r][c] = fma(aa[r], bb[c], acc[r][c]);
    }
#pragma unroll
    for (int r = 0; r < 4; ++r)
#pragma unroll
      for (int c = 0; c < 4; ++c) {
        int i = i0 + r, j = j0 + c;
        if (i < j) {
          float s = (float)acc[r][c];
          if (s >= KAPPA) {
            unsigned long long key =
                ((unsigned long long)mono_f32(s) << 16) |
                (unsigned)(65535 - ((i << 8) | j));
            int idx = atomicAdd(&misc[0], 1);
            if (idx < MCAP) keys[idx] = key;
          }
        }
      }
  }
  __syncthreads();
  if (tid == 0) {
    int c = misc[0];
    misc[1] = c > MCAP ? MCAP : c;
    misc[2] = c > MCAP ? 1 : 0;
    misc[3] = c > MCAP ? 0 : NMERGE;
  }
  __syncthreads();

  {
    const int e0 = 4 * tid;
    unsigned long long v0 = keys[e0], v1 = keys[e0 + 1],
                       v2 = keys[e0 + 2], v3 = keys[e0 + 3];
    for (int kk = 2; kk <= MCAP; kk <<= 1) {
      for (int jj = kk >> 1; jj > 0; jj >>= 1) {
        if (jj >= 256) {
          __syncthreads();
          keys[e0] = v0; keys[e0 + 1] = v1; keys[e0 + 2] = v2; keys[e0 + 3] = v3;
          __syncthreads();
          const int p0 = e0 ^ jj;
          unsigned long long o0 = keys[p0], o1 = keys[p0 + 1],
                             o2 = keys[p0 + 2], o3 = keys[p0 + 3];
          const bool km = ((e0 & kk) == 0) == ((e0 & jj) == 0);
          v0 = KEEP(v0, o0, km); v1 = KEEP(v1, o1, km);
          v2 = KEEP(v2, o2, km); v3 = KEEP(v3, o3, km);
        } else if (jj >= 4) {
          const int m = jj >> 2;
          unsigned long long o0 = shflx64(v0, m), o1 = shflx64(v1, m),
                             o2 = shflx64(v2, m), o3 = shflx64(v3, m);
          const bool km = ((e0 & kk) == 0) == ((e0 & jj) == 0);
          v0 = KEEP(v0, o0, km); v1 = KEEP(v1, o1, km);
          v2 = KEEP(v2, o2, km); v3 = KEEP(v3, o3, km);
        } else if (jj == 2) {
          const bool up = ((e0 & kk) == 0);
          CEX(v0, v2, up); CEX(v1, v3, up);
        } else {
          bool up0, up1;
          if (kk == 2) { up0 = true; up1 = false; }
          else { up0 = up1 = ((e0 & kk) == 0); }
          CEX(v0, v1, up0); CEX(v2, v3, up1);
        }
      }
    }
    __syncthreads();
    keys[e0] = v0; keys[e0 + 1] = v1; keys[e0 + 2] = v2; keys[e0 + 3] = v3;
  }
  __syncthreads();

  if (misc[2] == 0 && wid == 0) {
    const int cntC = misc[1];
    int rg0 = lane, rg1 = 64 + lane, rg2 = 128 + lane, rg3 = 192 + lane;
    int done = 0;
    for (int cursor = 0; cursor < cntC && done < NMERGE; cursor += 64) {
      const int idx = cursor + lane;
      const unsigned long long key = (idx < cntC) ? keys[idx] : 0ULL;
      const int pi = 255 - (int)((key >> 8) & 255);
      const int pj = 255 - (int)(key & 255);
      const int sli = pi & 63, ssi = pi >> 6;
      const int slj = pj & 63, ssj = pj >> 6;
      const int a0 = __shfl(rg0, sli), a1 = __shfl(rg1, sli),
                a2 = __shfl(rg2, sli), a3 = __shfl(rg3, sli);
      const int b0 = __shfl(rg0, slj), b1 = __shfl(rg1, slj),
                b2 = __shfl(rg2, slj), b3 = __shfl(rg3, slj);
      int gpi = (ssi == 0) ? a0 : (ssi == 1) ? a1 : (ssi == 2) ? a2 : a3;
      int gpj = (ssj == 0) ? b0 : (ssj == 1) ? b1 : (ssj == 2) ? b2 : b3;
      if (key == 0ULL) { gpi = 0; gpj = 0; }
      for (;;) {
        const unsigned long long mask = __ballot(gpi != gpj);
        if (!mask) break;
        const int f = __ffsll((long long)mask) - 1;
        const int gi = __shfl(gpi, f), gj = __shfl(gpj, f);
        if (lane == f) gpi = gpj;
        if (gpi == gi) gpi = gj;
        if (gpj == gi) gpj = gj;
        if (rg0 == gi) rg0 = gj;
        if (rg1 == gi) rg1 = gj;
        if (rg2 == gi) rg2 = gj;
        if (rg3 == gi) rg3 = gj;
        if (++done == NMERGE) break;
      }
    }
    gid[lane] = rg0; gid[64 + lane] = rg1;
    gid[128 + lane] = rg2; gid[192 + lane] = rg3;
    if (lane == 0) misc[3] = done;
  }
  __syncthreads();

  {
    const int start = misc[3];
    for (int mg = start; mg < NMERGE; ++mg) {
      unsigned long long best = 0ULL;
      const int p = tid >> 2, q = tid & 3;
      const int jA = 128 + p, jB = 127 - p;
      const int lenA = jA;
      int s0 = q * 64, s1 = (q == 3) ? 255 : (q * 64 + 64);
      for (int e = s0; e < s1; ++e) {
        int i = (e < lenA) ? e : (e - lenA);
        int j = (e < lenA) ? jA : jB;
        if (gid[i] != gid[j]) {
          double s = 0.0;
          for (int d = 0; d < 64; ++d)
            s = fma((double)knT[d * NTOK + i], (double)knT[d * NTOK + j], s);
          unsigned long long key =
              ((unsigned long long)mono_f32((float)s) << 16) |
              (unsigned)(65535 - ((i << 8) | j));
          if (key > best) best = key;
        }
      }
#pragma unroll
      for (int off = 32; off; off >>= 1) {
        unsigned long long o = __shfl_down(best, off);
        if (o > best) best = o;
      }
      if (lane == 0) red[wid] = best;
      __syncthreads();
      if (tid == 0) {
        unsigned long long mx = 0ULL;
        for (int w = 0; w < 8; ++w)
          if (red[w] > mx) mx = red[w];
        bkey[0] = mx;
      }
      __syncthreads();
      unsigned long long bk = bkey[0];
      int pi = 255 - (int)((bk >> 8) & 255);
      int pj = 255 - (int)(bk & 255);
      int gi = gid[pi], gj = gid[pj];
      __syncthreads();
      if (tid < 256 && gid[tid] == gi) gid[tid] = gj;
      __syncthreads();
    }
  }
  __syncthreads();

  if (tid < 256) cnt256[tid] = 0;
  __syncthreads();
  if (tid < 256) atomicAdd(&cnt256[gid[tid]], 1);
  __syncthreads();
  if (wid == 0) {
    const int t4 = lane * 4;
    const int c0 = cnt256[t4 + 0] != 0, c1 = cnt256[t4 + 1] != 0,
              c2 = cnt256[t4 + 2] != 0, c3 = cnt256[t4 + 3] != 0;
    const int tot = c0 + c1 + c2 + c3;
    int run = tot;
#pragma unroll
    for (int off = 1; off < 64; off <<= 1) {
      int o = __shfl_up(run, off);
      if (lane >= off) run += o;
    }
    const int bs = run - tot;
    scn[t4 + 0] = bs + c0;
    scn[t4 + 1] = bs + c0 + c1;
    scn[t4 + 2] = bs + c0 + c1 + c2;
    scn[t4 + 3] = bs + tot;
  }
  __syncthreads();
  if (tid < 256 && cnt256[tid]) rep[scn[tid] - 1] = tid;
  __syncthreads();
  for (int e = tid; e < NOUT * DIM; e += 512) accO[e] = 0.0f;
  __syncthreads();
  {
    const int t = tid >> 1, h = tid & 1;
    const int slot = scn[gid[t]] - 1;
    const float* vp = V + ((size_t)b * NTOK + t) * DIM + h * 32;
    float* dst = accO + slot * DIM + h * 32;
#pragma unroll
    for (int q = 0; q < 8; ++q) {
      float4 v4 = *reinterpret_cast<const float4*>(vp + q * 4);
      atomicAdd(&dst[q * 4 + 0], v4.x);
      atomicAdd(&dst[q * 4 + 1], v4.y);
      atomicAdd(&dst[q * 4 + 2], v4.z);
      atomicAdd(&dst[q * 4 + 3], v4.w);
    }
  }
  __syncthreads();

  float* outMain = OUT + (size_t)b * (NOUT * DIM);
  for (int e = tid; e < NOUT * DIM; e += 512) {
    int o = e >> 6;
    float sz = (float)cnt256[rep[o]];
    outMain[e] = accO[e] / sz;
  }
  float* outSz = OUT + (size_t)NB * NOUT * DIM + (size_t)b * NOUT;
  for (int o = tid; o < NOUT; o += 512) outSz[o] = (float)cnt256[rep[o]];
}

extern "C" void kernel_launch(void* const* d_in, const int* in_sizes, int n_in,
                              void* d_out, int out_size, void* d_ws, size_t ws_size,
                              hipStream_t stream) {
  const float* K = (const float*)d_in[0];
  const float* V = (const float*)d_in[1];
  float* OUT = (float*)d_out;
  (void)in_sizes; (void)n_in; (void)out_size;

  // ws: gcnt[128] @0 (512B), gflag[128] @512 (512B), gkeys @1024 (1MB),
  //     gid @1024+1MB (128KB)
  const size_t keysBytes = (size_t)NB * CAP * sizeof(unsigned long long);
  const size_t need = 1024 + keysBytes + (size_t)NB * NTOK * sizeof(int);
  if (ws_size >= need) {
    unsigned* gcnt = (unsigned*)d_ws;
    unsigned* gflag = (unsigned*)((char*)d_ws + 512);
    unsigned long long* gkeys = (unsigned long long*)((char*)d_ws + 1024);
    int* gidg = (int*)((char*)d_ws + 1024 + keysBytes);
    hipMemsetAsync(d_ws, 0, 1024, stream);
    hipFuncSetAttribute(reinterpret_cast<const void*>(gm_gram),
                        hipFuncAttributeMaxDynamicSharedMemorySize, SMEM_A);
    gm_gram<<<dim3(NB * 2), dim3(512), SMEM_A, stream>>>(K, gcnt, gflag, gkeys);
    gm_sortwalk<<<dim3(NB), dim3(256), 0, stream>>>(K, gcnt, gflag, gkeys, gidg);
    gm_epi<<<dim3(NB), dim3(256), 0, stream>>>(V, OUT, gidg);
  } else {
    hipFuncSetAttribute(reinterpret_cast<const void*>(gm_mono),
                        hipFuncAttributeMaxDynamicSharedMemorySize, SMEM_MONO);
    gm_mono<<<dim3(NB), dim3(512), SMEM_MONO, stream>>>(K, V, OUT);
  }
}

// Round 7
// 80.074 us; speedup vs baseline: 1.3739x; 1.0609x over previous
//
#include <hip/hip_runtime.h>
#include <stdint.h>

#define NTOK 256
#define NOUT 128
#define DIM 64
#define NB 128
#define CAP 1024
#define PCAP 1024
#define NMERGE 128
#define KAPPA 0.24f
#define SCREEN 0.2395f
#define NTILES84 1056

// LDS layout (bytes):
//   knT    [64][256] f32 : 65536 @ 0       (aliased by accO[128][64] after walk)
//   keys   [1024] u64    : 8192  @ 65536
//   lpairs [1024] u32    : 4096  @ 73728
//   gid    [256] i32     : 1024  @ 77824
//   claimA [256] u32     : 1024  @ 78848
//   gmap   [256] i32     : 1024  @ 79872
//   cnt256 [256] i32     : 1024  @ 80896
//   scn    [256] i32     : 1024  @ 81920
//   rep    [128] i32     : 512   @ 82944
//   red    [8] u64       : 64    @ 83456
//   bkey   u64           : 8     @ 83520
//   misc   [4] i32       : 16    @ 83528
#define SMEM_F 83584

__device__ __forceinline__ unsigned mono_f32(float s) {
  unsigned u = __float_as_uint(s);
  return (u & 0x80000000u) ? ~u : (u | 0x80000000u);
}

__device__ __forceinline__ unsigned long long shflx64(unsigned long long x, int m) {
  unsigned lo = (unsigned)x, hi = (unsigned)(x >> 32);
  lo = __shfl_xor(lo, m);
  hi = __shfl_xor(hi, m);
  return ((unsigned long long)hi << 32) | lo;
}

// invert T -> (ti, tj) on the 8x4 tile grid: ti in [0,32), tj in [2*ti, 64)
// cum(ti) = 65*ti - ti*ti
__device__ __forceinline__ void tile84(int T, int& tio, int& tjo) {
  float tf = (65.0f - sqrtf(4225.0f - 4.0f * (float)T)) * 0.5f;
  int t = (int)tf;
  if (t < 0) t = 0;
  if (t > 31) t = 31;
  while (t < 31 && 65 * (t + 1) - (t + 1) * (t + 1) <= T) ++t;
  while (t > 0 && 65 * t - t * t > T) --t;
  tio = t;
  tjo = 2 * t + (T - (65 * t - t * t));
}

#define CEX(a, b, up)                         \
  do {                                        \
    unsigned long long _a = (a), _b = (b);    \
    bool _sw = (up) ? (_a < _b) : (_a > _b);  \
    if (_sw) { (a) = _b; (b) = _a; }          \
  } while (0)

#define KEEP(v, o, km) ((km) ? ((v) > (o) ? (v) : (o)) : ((v) < (o) ? (v) : (o)))

// ============ fused kernel: gram + screen + sort + walk + epilogue ============
// grid 128 (1 WG/batch), block 512.
__global__ __launch_bounds__(512) void gm_fused(const float* __restrict__ K,
                                                const float* __restrict__ V,
                                                float* __restrict__ OUT) {
  extern __shared__ char smem[];
  float* knT = (float*)smem;
  float* accO = (float*)smem;  // alias: valid only after knT is dead
  unsigned long long* keys = (unsigned long long*)(smem + 65536);
  unsigned* lpairs = (unsigned*)(smem + 73728);
  int* gid = (int*)(smem + 77824);
  unsigned* claimA = (unsigned*)(smem + 78848);
  int* gmap = (int*)(smem + 79872);
  int* cnt256 = (int*)(smem + 80896);
  int* scn = (int*)(smem + 81920);
  int* rep = (int*)(smem + 82944);
  unsigned long long* red = (unsigned long long*)(smem + 83456);
  unsigned long long* bkey = (unsigned long long*)(smem + 83520);
  int* misc = (int*)(smem + 83528);

  const int tid = threadIdx.x;
  const int lane = tid & 63;
  const int wid = tid >> 6;
  const int b = blockIdx.x;

  if (tid == 0) { misc[0] = 0; misc[1] = 0; }
  if (tid < NTOK) {
    gid[tid] = tid;
    claimA[tid] = 0xFFFFFFFFu;
    gmap[tid] = -1;
  }

  // ---- phase 1: normalize -> knT[d][t] (bit-identical to prior rounds) ----
  {
    const int t = tid >> 1, h = tid & 1;
    const float* kp = K + ((size_t)b * NTOK + t) * DIM + h * 32;
    double ss = 0.0;
    float vals[32];
#pragma unroll
    for (int q = 0; q < 8; ++q) {
      float4 v4 = *reinterpret_cast<const float4*>(kp + q * 4);
      vals[q * 4 + 0] = v4.x; vals[q * 4 + 1] = v4.y;
      vals[q * 4 + 2] = v4.z; vals[q * 4 + 3] = v4.w;
      ss += (double)v4.x * v4.x + (double)v4.y * v4.y +
            (double)v4.z * v4.z + (double)v4.w * v4.w;
    }
    double other = __shfl_xor(ss, 1);
    double nrm = sqrt(ss + other);
#pragma unroll
    for (int q = 0; q < 32; ++q)
      knT[(h * 32 + q) * NTOK + t] = (float)((double)vals[q] / nrm);
  }
  __syncthreads();

  // ---- phase 2: f32 screen over 8x4 register tiles -> (i,j) pair list ----
  // Per-cell fmaf chain over ascending d: bit-identical to R6's screen.
  for (int t = tid; t < NTILES84; t += 512) {
    int ti, tj;
    tile84(t, ti, tj);
    const int i0 = ti * 8, j0 = tj * 4;

    float acc[8][4] = {};
#pragma unroll 4
    for (int d = 0; d < 64; ++d) {
      const float* row = knT + d * NTOK;
      const float4 a0 = *reinterpret_cast<const float4*>(row + i0);
      const float4 a1 = *reinterpret_cast<const float4*>(row + i0 + 4);
      const float4 bv = *reinterpret_cast<const float4*>(row + j0);
      const float aa[8] = {a0.x, a0.y, a0.z, a0.w, a1.x, a1.y, a1.z, a1.w};
      const float bb[4] = {bv.x, bv.y, bv.z, bv.w};
#pragma unroll
      for (int r = 0; r < 8; ++r)
#pragma unroll
        for (int c = 0; c < 4; ++c)
          acc[r][c] = fmaf(aa[r], bb[c], acc[r][c]);
    }
#pragma unroll
    for (int r = 0; r < 8; ++r)
#pragma unroll
      for (int c = 0; c < 4; ++c) {
        const int i = i0 + r, j = j0 + c;
        if (i < j && acc[r][c] >= SCREEN) {
          const int idx = atomicAdd(&misc[0], 1);
          if (idx < PCAP) lpairs[idx] = (unsigned)((i << 8) | j);
        }
      }
  }
  __syncthreads();

  // ---- phase 3: compact exact-f64 recompute -> keys[] in LDS ----
  const int npRaw = misc[0];
  const int np = npRaw > PCAP ? PCAP : npRaw;
  const bool fullFB = (npRaw > PCAP);
  for (int e = tid; e < np; e += 512) {
    const unsigned p = lpairs[e];
    const int i = (int)(p >> 8), j = (int)(p & 255u);
    double s = 0.0;
    for (int d = 0; d < 64; ++d)
      s = fma((double)knT[d * NTOK + i], (double)knT[d * NTOK + j], s);
    const float sf = (float)s;
    if (sf >= KAPPA) {
      const unsigned long long key =
          ((unsigned long long)mono_f32(sf) << 16) |
          (unsigned)(65535 - ((i << 8) | j));
      const int idx = atomicAdd(&misc[1], 1);
      keys[idx] = key;  // idx < np <= CAP always
    }
  }
  if (tid == 0) misc[3] = fullFB ? 0 : NMERGE;
  __syncthreads();
  const int nk = misc[1];

  // ---- phase 4: bitonic sort (descending) of 1024 keys, 2 keys/thread ----
  {
    const int e0 = 2 * tid;
    unsigned long long v0 = (e0 + 0 < nk) ? keys[e0 + 0] : 0ULL;
    unsigned long long v1 = (e0 + 1 < nk) ? keys[e0 + 1] : 0ULL;

    for (int kk = 2; kk <= CAP; kk <<= 1) {
      for (int jj = kk >> 1; jj > 0; jj >>= 1) {
        if (jj >= 128) {
          __syncthreads();
          keys[e0] = v0; keys[e0 + 1] = v1;
          __syncthreads();
          const int p0 = e0 ^ jj;
          const unsigned long long o0 = keys[p0], o1 = keys[p0 + 1];
          const bool km = ((e0 & kk) == 0) == ((e0 & jj) == 0);
          v0 = KEEP(v0, o0, km); v1 = KEEP(v1, o1, km);
        } else if (jj >= 2) {
          const int m = jj >> 1;
          const unsigned long long o0 = shflx64(v0, m), o1 = shflx64(v1, m);
          const bool km = ((e0 & kk) == 0) == ((e0 & jj) == 0);
          v0 = KEEP(v0, o0, km); v1 = KEEP(v1, o1, km);
        } else {
          const bool up = ((e0 & kk) == 0);
          CEX(v0, v1, up);
        }
      }
    }
    __syncthreads();
    keys[e0] = v0; keys[e0 + 1] = v1;
  }
  __syncthreads();

  // ---- phase 5: wave-0 walk over sorted keys (parallel disjoint rounds) ----
  if (!fullFB && wid == 0) {
    int done = 0;
    for (int cursor = 0; cursor < nk && done < NMERGE; cursor += 64) {
      const int idx = cursor + lane;
      const unsigned long long key = (idx < nk) ? keys[idx] : 0ULL;
      const int pi = 255 - (int)((key >> 8) & 255);
      const int pj = 255 - (int)(key & 255);
      int gpi = gid[pi];
      int gpj = gid[pj];
      if (key == 0ULL) { gpi = 0; gpj = 0; }  // padding -> invalid
      int rg0 = gid[lane], rg1 = gid[64 + lane],
          rg2 = gid[128 + lane], rg3 = gid[192 + lane];

      unsigned long long valid = __ballot(gpi != gpj);
      if (done + (int)__popcll(valid) < NMERGE) {
        // parallel rounds: commit all prefix-disjoint merges
        while (valid) {
          const bool v = (gpi != gpj);
          if (v) {
            atomicMin(&claimA[gpi], (unsigned)lane);
            atomicMin(&claimA[gpj], (unsigned)lane);
          }
          __threadfence_block();
          const bool win = v && (claimA[gpi] == (unsigned)lane) &&
                           (claimA[gpj] == (unsigned)lane);
          if (win) gmap[gpi] = gpj;
          __threadfence_block();
          const int ogpi = gpi, ogpj = gpj;
          {
            const int m0 = gmap[rg0], m1 = gmap[rg1],
                      m2 = gmap[rg2], m3 = gmap[rg3];
            const int mi = gmap[ogpi], mj = gmap[ogpj];
            if (m0 >= 0) rg0 = m0;
            if (m1 >= 0) rg1 = m1;
            if (m2 >= 0) rg2 = m2;
            if (m3 >= 0) rg3 = m3;
            if (mi >= 0) gpi = mi;
            if (mj >= 0) gpj = mj;
          }
          if (v) { claimA[ogpi] = 0xFFFFFFFFu; claimA[ogpj] = 0xFFFFFFFFu; }
          if (win) gmap[ogpi] = -1;
          __threadfence_block();
          done += (int)__popcll(__ballot(win));
          valid = __ballot(gpi != gpj);
        }
      } else {
        // serial mode near budget: exact cutoff at NMERGE
        for (;;) {
          const unsigned long long mask = __ballot(gpi != gpj);
          if (!mask) break;
          const int f = __ffsll((long long)mask) - 1;
          const int gij = __shfl((gpi << 8) | gpj, f);
          const int gi = gij >> 8, gj = gij & 255;
          if (gpi == gi) gpi = gj;
          if (gpj == gi) gpj = gj;
          if (rg0 == gi) rg0 = gj;
          if (rg1 == gi) rg1 = gj;
          if (rg2 == gi) rg2 = gj;
          if (rg3 == gi) rg3 = gj;
          if (++done == NMERGE) break;
        }
      }
      gid[lane] = rg0; gid[64 + lane] = rg1;
      gid[128 + lane] = rg2; gid[192 + lane] = rg3;
      __threadfence_block();
    }
    if (lane == 0) misc[3] = done;
  }
  __syncthreads();

  // ---- phase 6: exact fallback (never taken in practice), uses knT ----
  {
    const int start = misc[3];
    for (int mg = start; mg < NMERGE; ++mg) {
      unsigned long long best = 0ULL;
      const int p = tid >> 2, q = tid & 3;
      const int jA = 128 + p, jB = 127 - p;
      const int lenA = jA;
      const int s0 = q * 64, s1 = (q == 3) ? 255 : (q * 64 + 64);
      for (int e = s0; e < s1; ++e) {
        const int i = (e < lenA) ? e : (e - lenA);
        const int j = (e < lenA) ? jA : jB;
        if (gid[i] != gid[j]) {
          double s = 0.0;
          for (int d = 0; d < 64; ++d)
            s = fma((double)knT[d * NTOK + i], (double)knT[d * NTOK + j], s);
          const unsigned long long key =
              ((unsigned long long)mono_f32((float)s) << 16) |
              (unsigned)(65535 - ((i << 8) | j));
          if (key > best) best = key;
        }
      }
#pragma unroll
      for (int off = 32; off; off >>= 1) {
        unsigned long long o = __shfl_down(best, off);
        if (o > best) best = o;
      }
      if (lane == 0) red[wid] = best;
      __syncthreads();
      if (tid == 0) {
        unsigned long long mx = red[0];
        for (int w = 1; w < 8; ++w)
          if (red[w] > mx) mx = red[w];
        bkey[0] = mx;
      }
      __syncthreads();
      const unsigned long long bk = bkey[0];
      const int pi = 255 - (int)((bk >> 8) & 255);
      const int pj = 255 - (int)(bk & 255);
      const int gi = gid[pi], gj = gid[pj];
      __syncthreads();
      if (tid < NTOK && gid[tid] == gi) gid[tid] = gj;
      __syncthreads();
    }
  }
  __syncthreads();
  // knT is DEAD from here; accO (alias of knT) becomes live.

  // ---- phase 7: sizes + single-wave prefix scan + slots ----
  if (tid < NTOK) cnt256[tid] = 0;
  for (int e = tid; e < NOUT * DIM; e += 512) accO[e] = 0.0f;
  __syncthreads();
  if (tid < NTOK) atomicAdd(&cnt256[gid[tid]], 1);
  __syncthreads();
  if (wid == 0) {
    const int t4 = lane * 4;
    const int c0 = cnt256[t4 + 0] != 0, c1 = cnt256[t4 + 1] != 0,
              c2 = cnt256[t4 + 2] != 0, c3 = cnt256[t4 + 3] != 0;
    const int tot = c0 + c1 + c2 + c3;
    int run = tot;
#pragma unroll
    for (int off = 1; off < 64; off <<= 1) {
      int o = __shfl_up(run, off);
      if (lane >= off) run += o;
    }
    const int bs = run - tot;
    scn[t4 + 0] = bs + c0;
    scn[t4 + 1] = bs + c0 + c1;
    scn[t4 + 2] = bs + c0 + c1 + c2;
    scn[t4 + 3] = bs + tot;
  }
  __syncthreads();
  if (tid < NTOK && cnt256[tid]) rep[scn[tid] - 1] = tid;
  __syncthreads();

  // ---- phase 8: accumulate V into slots (token tid>>1, half tid&1) ----
  {
    const int t = tid >> 1, h = tid & 1;
    const int slot = scn[gid[t]] - 1;
    const float* vp = V + ((size_t)b * NTOK + t) * DIM + h * 32;
    float* dst = accO + slot * DIM + h * 32;
#pragma unroll
    for (int q = 0; q < 8; ++q) {
      float4 v4 = *reinterpret_cast<const float4*>(vp + q * 4);
      atomicAdd(&dst[q * 4 + 0], v4.x);
      atomicAdd(&dst[q * 4 + 1], v4.y);
      atomicAdd(&dst[q * 4 + 2], v4.z);
      atomicAdd(&dst[q * 4 + 3], v4.w);
    }
  }
  __syncthreads();

  // ---- phase 9: write outputs ----
  float* outMain = OUT + (size_t)b * (NOUT * DIM);
  for (int e = tid; e < NOUT * DIM; e += 512) {
    const int o = e >> 6;
    const float sz = (float)cnt256[rep[o]];
    outMain[e] = accO[e] / sz;
  }
  float* outSz = OUT + (size_t)NB * NOUT * DIM + (size_t)b * NOUT;
  for (int o = tid; o < NOUT; o += 512) outSz[o] = (float)cnt256[rep[o]];
}

extern "C" void kernel_launch(void* const* d_in, const int* in_sizes, int n_in,
                              void* d_out, int out_size, void* d_ws, size_t ws_size,
                              hipStream_t stream) {
  const float* K = (const float*)d_in[0];
  const float* V = (const float*)d_in[1];
  float* OUT = (float*)d_out;
  (void)in_sizes; (void)n_in; (void)out_size; (void)d_ws; (void)ws_size;

  hipFuncSetAttribute(reinterpret_cast<const void*>(gm_fused),
                      hipFuncAttributeMaxDynamicSharedMemorySize, SMEM_F);
  gm_fused<<<dim3(NB), dim3(512), SMEM_F, stream>>>(K, V, OUT);
}